// Round 1
// baseline (926.051 us; speedup 1.0000x reference)
//
#include <hip/hip_runtime.h>

#define NP 16
#define D 768
#define PST 776  // padded LDS stride for sums (776 % 32 == 8 -> spreads banks per proto)

// ws layout (floats):
// [0, 12288)      normalized prototypes
// [12288, 24576)  global sums accumulator
// [24576, 24592)  global counts accumulator

__global__ __launch_bounds__(64) void setup_kernel(const float* __restrict__ protos,
                                                   float* __restrict__ ws) {
    const int p = blockIdx.x;     // 0..15
    const int lane = threadIdx.x; // 0..63

    // zero this proto's slice of the global accumulators
    float* gsum = ws + 12288 + p * D;
    for (int j = lane; j < D; j += 64) gsum[j] = 0.f;
    if (lane == 0) ws[24576 + p] = 0.f;

    // row-normalize prototype p
    const float* pr = protos + p * D;
    float v[12];
    float ns = 0.f;
#pragma unroll
    for (int j = 0; j < 12; ++j) {
        v[j] = pr[lane + 64 * j];
        ns = fmaf(v[j], v[j], ns);
    }
#pragma unroll
    for (int m = 1; m < 64; m <<= 1) ns += __shfl_xor(ns, m);
    const float rn = 1.0f / sqrtf(ns);
    float* pn = ws + p * D;
#pragma unroll
    for (int j = 0; j < 12; ++j) pn[lane + 64 * j] = v[j] * rn;
}

__global__ __launch_bounds__(512, 2) void assign_accum_kernel(
    const float* __restrict__ x, const float* __restrict__ ws,
    float* __restrict__ gsum, float* __restrict__ gcnt, int nrows) {
    __shared__ float sP[NP * D];    // 48 KB: normalized protos
    __shared__ float sS[NP * PST];  // ~49.7 KB: per-block segment sums (padded)
    __shared__ float sC[NP];

    const int tid = threadIdx.x;

    for (int i = tid; i < NP * D; i += 512) sP[i] = ws[i];
    for (int i = tid; i < NP * PST; i += 512) sS[i] = 0.f;
    if (tid < NP) sC[tid] = 0.f;
    __syncthreads();

    const int wave = tid >> 6;
    const int lane = tid & 63;
    const int k = lane & 15;   // d-slice owner within a row (16 lanes/row)
    const int g = lane >> 4;   // row-group within the wave (4 rows/tile)

    const int ntiles = (nrows + 63) >> 6;  // 64 rows per block-iteration
    for (int t = blockIdx.x; t < ntiles; t += gridDim.x) {
        const int rowbase = (t << 6) + (wave << 3) + g;
        const int r0 = rowbase;      // tile 0
        const int r1 = rowbase + 4;  // tile 1
        const bool v0 = r0 < nrows;
        const bool v1 = r1 < nrows;
        const int r0c = v0 ? r0 : 0;
        const int r1c = v1 ? r1 : 0;

        // load 8 rows worth: each lane 48 floats per row slice
        float4 xa[12], xb[12];
        const float4* p0 = reinterpret_cast<const float4*>(x + (size_t)r0c * D + k * 4);
        const float4* p1 = reinterpret_cast<const float4*>(x + (size_t)r1c * D + k * 4);
#pragma unroll
        for (int j = 0; j < 12; ++j) {
            xa[j] = p0[j * 16];  // stride 64 floats
            xb[j] = p1[j * 16];
        }

        float ns0 = 0.f, ns1 = 0.f;
        float d0[NP], d1[NP];
#pragma unroll
        for (int p = 0; p < NP; ++p) { d0[p] = 0.f; d1[p] = 0.f; }

#pragma unroll
        for (int j = 0; j < 12; ++j) {
            const float4 a = xa[j];
            const float4 b = xb[j];
            ns0 = fmaf(a.x, a.x, fmaf(a.y, a.y, fmaf(a.z, a.z, fmaf(a.w, a.w, ns0))));
            ns1 = fmaf(b.x, b.x, fmaf(b.y, b.y, fmaf(b.z, b.z, fmaf(b.w, b.w, ns1))));
#pragma unroll
            for (int p = 0; p < NP; ++p) {
                const float4 pv = *reinterpret_cast<const float4*>(&sP[p * D + j * 64 + k * 4]);
                d0[p] = fmaf(a.x, pv.x, fmaf(a.y, pv.y, fmaf(a.z, pv.z, fmaf(a.w, pv.w, d0[p]))));
                d1[p] = fmaf(b.x, pv.x, fmaf(b.y, pv.y, fmaf(b.z, pv.z, fmaf(b.w, pv.w, d1[p]))));
            }
        }

        // reduce across the 16 lanes of each row-group
#pragma unroll
        for (int m = 1; m <= 8; m <<= 1) {
            ns0 += __shfl_xor(ns0, m);
            ns1 += __shfl_xor(ns1, m);
#pragma unroll
            for (int p = 0; p < NP; ++p) {
                d0[p] += __shfl_xor(d0[p], m);
                d1[p] += __shfl_xor(d1[p], m);
            }
        }

        // argmax similarity == argmin distance (first-index tie-break via strict >)
        int a0 = 0, a1 = 0;
        float m0 = d0[0], m1 = d1[0];
#pragma unroll
        for (int p = 1; p < NP; ++p) {
            if (d0[p] > m0) { m0 = d0[p]; a0 = p; }
            if (d1[p] > m1) { m1 = d1[p]; a1 = p; }
        }
        const float rn0 = 1.0f / sqrtf(ns0);
        const float rn1 = 1.0f / sqrtf(ns1);

        if (v0) {
            float* dst = sS + a0 * PST + k * 4;
#pragma unroll
            for (int j = 0; j < 12; ++j) {
                atomicAdd(dst + j * 64 + 0, xa[j].x * rn0);
                atomicAdd(dst + j * 64 + 1, xa[j].y * rn0);
                atomicAdd(dst + j * 64 + 2, xa[j].z * rn0);
                atomicAdd(dst + j * 64 + 3, xa[j].w * rn0);
            }
            if (k == 0) atomicAdd(&sC[a0], 1.0f);
        }
        if (v1) {
            float* dst = sS + a1 * PST + k * 4;
#pragma unroll
            for (int j = 0; j < 12; ++j) {
                atomicAdd(dst + j * 64 + 0, xb[j].x * rn1);
                atomicAdd(dst + j * 64 + 1, xb[j].y * rn1);
                atomicAdd(dst + j * 64 + 2, xb[j].z * rn1);
                atomicAdd(dst + j * 64 + 3, xb[j].w * rn1);
            }
            if (k == 0) atomicAdd(&sC[a1], 1.0f);
        }
    }

    __syncthreads();
    // flush block partials to global accumulators
    for (int i = tid; i < NP * D; i += 512) {
        const int p = i / D;
        const int d = i - p * D;
        atomicAdd(&gsum[i], sS[p * PST + d]);
    }
    if (tid < NP) atomicAdd(&gcnt[tid], sC[tid]);
}

__global__ __launch_bounds__(256) void finalize_kernel(const float* __restrict__ ws,
                                                       float* __restrict__ out) {
    const int i = blockIdx.x * blockDim.x + threadIdx.x;
    if (i < NP * D) {
        const int p = i / D;
        const float c = ws[24576 + p];
        const float s = ws[12288 + i];
        out[i] = (c > 0.f) ? s / fmaxf(c, 1.0f) : 0.f;
    }
}

extern "C" void kernel_launch(void* const* d_in, const int* in_sizes, int n_in,
                              void* d_out, int out_size, void* d_ws, size_t ws_size,
                              hipStream_t stream) {
    const float* x = (const float*)d_in[0];
    const float* protos = (const float*)d_in[1];
    float* ws = (float*)d_ws;
    float* out = (float*)d_out;
    const int nrows = in_sizes[0] / D;  // 200000

    setup_kernel<<<16, 64, 0, stream>>>(protos, ws);
    assign_accum_kernel<<<256, 512, 0, stream>>>(x, ws, ws + 12288, ws + 24576, nrows);
    finalize_kernel<<<(NP * D + 255) / 256, 256, 0, stream>>>(ws, out);
}